// Round 2
// baseline (1759.026 us; speedup 1.0000x reference)
//
#include <hip/hip_runtime.h>

// CHIVE clockwork RNN, fp32 — round 2: in-register state broadcast.
// R1 post-mortem: LDS-throughput-bound (122 KB/CU/step of ds_read_b128
// broadcasts ~= 1434 cyc at 85 B/cyc = measured 1468 cyc/step). This round
// keeps all recurrent state in lane registers and performs the 32-wide
// broadcast-matmuls with a 4-chain gray-code hypercube tour:
//   init: 3x ds_swizzle (xor 8/16/24), transitions: v_mov_dpp quad_perm
//   (xor1/xor2, VALU pipe) + 1 xor4 swizzle per chain.
// Weights preloaded per-lane in tour-permuted order, pinned in VGPRs.

constexpr int TS  = 2048;
constexpr int B   = 2048;
constexpr int HH  = 32;
constexpr int CH  = 16;   // timesteps per staged chunk
constexpr int NCH = TS / CH;
constexpr int BPB = 8;    // batch per block

// xor1 within quads: perm [1,0,3,2] -> 1|(0<<2)|(3<<4)|(2<<6) = 0xB1
#define XD1(x) __int_as_float(__builtin_amdgcn_mov_dpp(__float_as_int(x), 0xB1, 0xF, 0xF, true))
// xor2 within quads: perm [2,3,0,1] -> 2|(3<<2)|(0<<4)|(1<<6) = 0x4E
#define XD2(x) __int_as_float(__builtin_amdgcn_mov_dpp(__float_as_int(x), 0x4E, 0xF, 0xF, true))
// ds_swizzle BitMode: offset = (xor<<10) | 0x1F
#define SWZ(x, imm) __int_as_float(__builtin_amdgcn_ds_swizzle(__float_as_int(x), imm))

__device__ __forceinline__ float fast_tanh(float x) {
    x = fminf(fmaxf(x, -9.0f), 9.0f);
    float e = __expf(2.0f * x);
    return (e - 1.0f) * __builtin_amdgcn_rcpf(e + 1.0f);
}

// sum_k v_k * W[k][j], lane j holds v_j. wt is tour-permuted:
// wt[c*8+i] = W[(j ^ ((c<<3)|g3[i]))][j], g3 = {0,1,3,2,6,7,5,4}.
__device__ __forceinline__ float dot32(float v, const float* wt) {
    float r0 = v;
    float r1 = SWZ(v, 0x201F);   // xor 8
    float r2 = SWZ(v, 0x401F);   // xor 16
    float r3 = SWZ(v, 0x601F);   // xor 24
    float a0 = r0 * wt[0], a1 = r1 * wt[8], a2 = r2 * wt[16], a3 = r3 * wt[24];
    r0 = XD1(r0); r1 = XD1(r1); r2 = XD1(r2); r3 = XD1(r3);
    a0 = fmaf(r0, wt[1], a0); a1 = fmaf(r1, wt[9],  a1);
    a2 = fmaf(r2, wt[17], a2); a3 = fmaf(r3, wt[25], a3);
    r0 = XD2(r0); r1 = XD2(r1); r2 = XD2(r2); r3 = XD2(r3);
    a0 = fmaf(r0, wt[2], a0); a1 = fmaf(r1, wt[10], a1);
    a2 = fmaf(r2, wt[18], a2); a3 = fmaf(r3, wt[26], a3);
    r0 = XD1(r0); r1 = XD1(r1); r2 = XD1(r2); r3 = XD1(r3);
    a0 = fmaf(r0, wt[3], a0); a1 = fmaf(r1, wt[11], a1);
    a2 = fmaf(r2, wt[19], a2); a3 = fmaf(r3, wt[27], a3);
    r0 = SWZ(r0, 0x101F); r1 = SWZ(r1, 0x101F);   // xor 4
    r2 = SWZ(r2, 0x101F); r3 = SWZ(r3, 0x101F);
    a0 = fmaf(r0, wt[4], a0); a1 = fmaf(r1, wt[12], a1);
    a2 = fmaf(r2, wt[20], a2); a3 = fmaf(r3, wt[28], a3);
    r0 = XD1(r0); r1 = XD1(r1); r2 = XD1(r2); r3 = XD1(r3);
    a0 = fmaf(r0, wt[5], a0); a1 = fmaf(r1, wt[13], a1);
    a2 = fmaf(r2, wt[21], a2); a3 = fmaf(r3, wt[29], a3);
    r0 = XD2(r0); r1 = XD2(r1); r2 = XD2(r2); r3 = XD2(r3);
    a0 = fmaf(r0, wt[6], a0); a1 = fmaf(r1, wt[14], a1);
    a2 = fmaf(r2, wt[22], a2); a3 = fmaf(r3, wt[30], a3);
    r0 = XD1(r0); r1 = XD1(r1); r2 = XD1(r2); r3 = XD1(r3);
    a0 = fmaf(r0, wt[7], a0); a1 = fmaf(r1, wt[15], a1);
    a2 = fmaf(r2, wt[23], a2); a3 = fmaf(r3, wt[31], a3);
    return (a0 + a1) + (a2 + a3);
}

// sum_k v_k * W[k][j] over k=0..7; lane j holds v_{j&7}.
// wt[c*4+i] = W[((j&7) ^ ((c<<2)|g2[i]))][j], g2 = {0,1,3,2}.
__device__ __forceinline__ float dot8(float v, const float* wt) {
    float r0 = v;
    float r1 = SWZ(v, 0x101F);   // xor 4
    float a0 = r0 * wt[0], a1 = r1 * wt[4];
    r0 = XD1(r0); r1 = XD1(r1);
    a0 = fmaf(r0, wt[1], a0); a1 = fmaf(r1, wt[5], a1);
    r0 = XD2(r0); r1 = XD2(r1);
    a0 = fmaf(r0, wt[2], a0); a1 = fmaf(r1, wt[6], a1);
    r0 = XD1(r0); r1 = XD1(r1);
    a0 = fmaf(r0, wt[3], a0); a1 = fmaf(r1, wt[7], a1);
    return a0 + a1;
}

__global__ __launch_bounds__(256, 1)
void chive_rnn(const float* __restrict__ frnn, const float* __restrict__ phrnn,
               const float* __restrict__ syl,
               const float* __restrict__ Wxf, const float* __restrict__ Whf,
               const float* __restrict__ bf,
               const float* __restrict__ Wxp, const float* __restrict__ Whp,
               const float* __restrict__ bp,
               const float* __restrict__ Wxs, const float* __restrict__ Whs,
               const float* __restrict__ bs,
               const int* __restrict__ fclock, const int* __restrict__ pclock,
               const int* __restrict__ sfreq, float* __restrict__ out)
{
    __shared__ __align__(16) float xfb[2][CH][BPB * 8];
    __shared__ __align__(16) float xpb[2][CH][BPB * 8];
    __shared__ __align__(16) float xsb[2][CH][BPB * 32];  // 24 real + 8 zero pad
    __shared__ int gates[TS];

    const int tid = threadIdx.x;
    const int j   = tid & 31;   // hidden index == lane within 32-group
    const int g   = tid >> 5;   // batch-in-block
    const int b0  = blockIdx.x * BPB;

    // ---- tour-permuted per-lane weight columns ----
    const int g3v[8] = {0, 1, 3, 2, 6, 7, 5, 4};
    const int g2v[4] = {0, 1, 3, 2};
    float whf_t[32], whp_t[32], wxs_t[32], whs_t[32], wxf_t[8], wxp_t[8];
#pragma unroll
    for (int c = 0; c < 4; c++) {
#pragma unroll
        for (int i = 0; i < 8; i++) {
            const int k = j ^ ((c << 3) | g3v[i]);
            whf_t[c * 8 + i] = Whf[k * HH + j];
            whp_t[c * 8 + i] = Whp[k * HH + j];
            wxs_t[c * 8 + i] = Wxs[k * HH + j];
            whs_t[c * 8 + i] = Whs[k * HH + j];
        }
    }
#pragma unroll
    for (int c = 0; c < 2; c++) {
#pragma unroll
        for (int i = 0; i < 4; i++) {
            const int k = (j & 7) ^ ((c << 2) | g2v[i]);
            wxf_t[c * 4 + i] = Wxf[k * HH + j];
            wxp_t[c * 4 + i] = Wxp[k * HH + j];
        }
    }
    const float bfj = bf[j], bpj = bp[j], bsj = bs[j];

    // Pin weights in VGPRs (prevents the compiler re-loading them in-loop;
    // R1 had VGPR_Count=140 < 144 weight floats -> in-loop reloads).
#pragma unroll
    for (int i = 0; i < 32; i++) {
        asm volatile("" : "+v"(whf_t[i]), "+v"(whp_t[i]), "+v"(wxs_t[i]), "+v"(whs_t[i]));
    }
#pragma unroll
    for (int i = 0; i < 8; i++) {
        asm volatile("" : "+v"(wxf_t[i]), "+v"(wxp_t[i]));
    }

    // ---- chunk staging (register prefetch -> LDS double buffer) ----
    const int tl = tid >> 4;   // 0..15: timestep row this thread loads
    const int q  = tid & 15;   // 0..15: slot within the row
    // syl row: 48 real float4 (8 batches x 6), this thread handles r = q, q+16, q+32
    int sb_[3], ss_[3];
#pragma unroll
    for (int u = 0; u < 3; u++) {
        const int r = q + 16 * u;
        sb_[u] = r / 6;
        ss_[u] = r - 6 * sb_[u];
    }
    const int zslot = ((q >> 1) * 8 + 6 + (q & 1)) * 4;  // float offset of this thread's zero-pad f4

    float4 rf, rp, rsA, rsB, rsC;
    auto load_chunk = [&](int ch) {
        const size_t t  = (size_t)ch * CH + tl;
        const float* fb = frnn  + (t * B + b0) * 8;
        const float* pb = phrnn + (t * B + b0) * 8;
        const float* sb = syl   + (t * B + b0) * 24;
        rf  = *(const float4*)(fb + q * 4);
        rp  = *(const float4*)(pb + q * 4);
        rsA = *(const float4*)(sb + (q +  0) * 4);
        rsB = *(const float4*)(sb + (q + 16) * 4);
        rsC = *(const float4*)(sb + (q + 32) * 4);
    };
    auto store_chunk = [&](int buf) {
        *(float4*)&xfb[buf][tl][q * 4] = rf;
        *(float4*)&xpb[buf][tl][q * 4] = rp;
        *(float4*)&xsb[buf][tl][(sb_[0] * 8 + ss_[0]) * 4] = rsA;
        *(float4*)&xsb[buf][tl][(sb_[1] * 8 + ss_[1]) * 4] = rsB;
        *(float4*)&xsb[buf][tl][(sb_[2] * 8 + ss_[2]) * 4] = rsC;
        const float4 z4 = {0.f, 0.f, 0.f, 0.f};
        *(float4*)&xsb[buf][tl][zslot] = z4;
    };

    load_chunk(0);

    // ---- gate precompute ----
    for (int i = tid; i < TS; i += 256) {
        const int mf = fclock[i] + 1;
        const int mp = pclock[i] + 1;
        int v = 0;
        if ((i % mf) == 0) v |= 1;
        if ((i % mp) == 0) v |= 2;
        if (sfreq[i] == 1) v |= 4;
        gates[i] = v;
    }

    store_chunk(0);
    __syncthreads();

    // ---- recurrent state: pure registers (lane j owns element j of batch g) ----
    float vhf = 0.f, vhp = 0.f, vhs0 = 0.f, vhs1 = 0.f, vhs2 = 0.f;

    int cur = 0;
#pragma unroll 1
    for (int ch = 0; ch < NCH; ch++) {
        if (ch + 1 < NCH) load_chunk(ch + 1);

#pragma unroll 1
        for (int c = 0; c < CH; c++) {
            const int t  = ch * CH + c;
            const int gt = __builtin_amdgcn_readfirstlane(gates[t]);

            if (gt & 1) {   // f cell
                const float xf = xfb[cur][c][g * 8 + (j & 7)];
                vhf = fast_tanh(bfj + dot8(xf, wxf_t) + dot32(vhf, whf_t));
            }
            if (gt & 2) {   // p cell
                const float xp = xpb[cur][c][g * 8 + (j & 7)];
                vhp = fast_tanh(bpj + dot8(xp, wxp_t) + dot32(vhp, whp_t));
            }
            if (gt & 4) {   // syl cell: x = {hf, hp, x_syl(zero-padded)}
                const float xs = xsb[cur][c][g * 32 + j];
                const float p0 = bsj + dot32(vhf, wxs_t) + dot32(vhs0, whs_t);
                const float p1 = bsj + dot32(vhp, wxs_t) + dot32(vhs1, whs_t);
                const float p2 = bsj + dot32(xs,  wxs_t) + dot32(vhs2, whs_t);
                vhs0 = fast_tanh(p0);
                vhs1 = fast_tanh(p1);
                vhs2 = fast_tanh(p2);
            }
        }

        if (ch + 1 < NCH) store_chunk(cur ^ 1);
        __syncthreads();
        cur ^= 1;
    }

    // ---- output: h_s final, [3, B, H], straight from registers ----
    const int b = b0 + g;
    out[((size_t)0 * B + b) * HH + j] = vhs0;
    out[((size_t)1 * B + b) * HH + j] = vhs1;
    out[((size_t)2 * B + b) * HH + j] = vhs2;
}

extern "C" void kernel_launch(void* const* d_in, const int* in_sizes, int n_in,
                              void* d_out, int out_size, void* d_ws, size_t ws_size,
                              hipStream_t stream) {
    const float* frnn  = (const float*)d_in[0];
    const float* phrnn = (const float*)d_in[1];
    const float* syl   = (const float*)d_in[2];
    const float* Wxf   = (const float*)d_in[3];
    const float* Whf   = (const float*)d_in[4];
    const float* bf    = (const float*)d_in[5];
    const float* Wxp   = (const float*)d_in[6];
    const float* Whp   = (const float*)d_in[7];
    const float* bp    = (const float*)d_in[8];
    const float* Wxs   = (const float*)d_in[9];
    const float* Whs   = (const float*)d_in[10];
    const float* bs    = (const float*)d_in[11];
    const int* fclock  = (const int*)d_in[12];
    const int* pclock  = (const int*)d_in[13];
    const int* sfreq   = (const int*)d_in[14];
    float* out = (float*)d_out;

    dim3 grid(B / BPB);   // 256 blocks, 1 per CU
    dim3 block(256);
    chive_rnn<<<grid, block, 0, stream>>>(frnn, phrnn, syl,
                                          Wxf, Whf, bf, Wxp, Whp, bp,
                                          Wxs, Whs, bs,
                                          fclock, pclock, sfreq, out);
}